// Round 8
// baseline (1213.631 us; speedup 1.0000x reference)
//
#include <hip/hip_runtime.h>
#include <hip/hip_cooperative_groups.h>

namespace cg = cooperative_groups;

#define NEG_SLOPE 0.2f
#define CH 4096      // edges per partition chunk
#define BSTRIDE 1536 // padded words per bucket (mean 1024, sigma 32 -> +16 sigma)

__device__ inline unsigned short f2bf(float f) {
    unsigned u = __float_as_uint(f);
    unsigned r = (u + 0x7FFFu + ((u >> 16) & 1u)) >> 16;
    return (unsigned short)r;
}
__device__ inline unsigned pack2bf(float a, float b) {
    return (unsigned)f2bf(a) | ((unsigned)f2bf(b) << 16);
}
__device__ inline float bf2f_lo(unsigned u) { return __uint_as_float(u << 16); }
__device__ inline float bf2f_hi(unsigned u) { return __uint_as_float(u & 0xFFFF0000u); }
__device__ inline float lrelu(float v) { return v > 0.f ? v : NEG_SLOPE * v; }

#define FMA8(A, F, S)                          \
    A[0] = fmaf(bf2f_lo((F).x), S, A[0]);      \
    A[1] = fmaf(bf2f_hi((F).x), S, A[1]);      \
    A[2] = fmaf(bf2f_lo((F).y), S, A[2]);      \
    A[3] = fmaf(bf2f_hi((F).y), S, A[3]);      \
    A[4] = fmaf(bf2f_lo((F).z), S, A[4]);      \
    A[5] = fmaf(bf2f_hi((F).z), S, A[5]);      \
    A[6] = fmaf(bf2f_lo((F).w), S, A[6]);      \
    A[7] = fmaf(bf2f_hi((F).w), S, A[7]);

// ===========================================================================
// Single cooperative persistent kernel. 512 threads/block, grid sized to
// exact co-residency. Phases separated by grid.sync(); work items pulled
// from global atomic queues (qcnt[0..3]) for load balance.
//   P0 init  -> P1 partition+gemm1 -> P2 gather1 -> P3 gemm2 -> P4 gather2
// ===========================================================================
__global__ __launch_bounds__(512) void gat_all(
    const int* __restrict__ src, const int* __restrict__ dst,
    const float* __restrict__ h, const float* __restrict__ W1,
    const float* __restrict__ al1, const float* __restrict__ ar1,
    const float* __restrict__ b1, const float* __restrict__ W2,
    const float* __restrict__ al2, const float* __restrict__ ar2,
    const float* __restrict__ b2, int* __restrict__ bucket_cursor,
    int* __restrict__ qcnt, unsigned* __restrict__ tmp,
    float* __restrict__ el1, float* __restrict__ er1,
    unsigned short* __restrict__ feat1b, unsigned short* __restrict__ out1b,
    float* __restrict__ el2, float* __restrict__ er2,
    unsigned short* __restrict__ feat2b, float* __restrict__ out2,
    int E, int NB, int nchunks, int N) {
    cg::grid_group grid = cg::this_grid();
    __shared__ __align__(16) int smem[8192];  // 32 KB union
    __shared__ int item_sh;
    const int tid = threadIdx.x;

    // ---------------- phase 0: init cursors + queue heads ----------------
    for (int i = (int)blockIdx.x * 512 + tid; i < NB + 8; i += (int)gridDim.x * 512) {
        if (i < NB) bucket_cursor[i] = 0;
        else qcnt[i - NB] = 0;
    }
    grid.sync();

    // ---------------- phase 1: partition chunks + gemm1 tiles ----------------
    const int g1tiles = (N + 63) >> 6;
    const int total1 = nchunks + g1tiles;
    for (;;) {
        if (tid == 0) item_sh = atomicAdd(&qcnt[0], 1);
        __syncthreads();
        const int item = item_sh;
        if (item >= total1) break;
        if (item < nchunks) {
            // ---- partition body (512 threads) ----
            int* lh = smem;                               // 1024
            int* lex = smem + 1024;                       // 1024
            int* gbase_sh = smem + 2048;                  // 1024
            int* wsum = smem + 3072;                      // 8
            unsigned* sortedv = (unsigned*)(smem + 3088); // 4096
            const int base_e = item * CH;
            const int cnt_e = min(CH, E - base_e);
            for (int i = tid; i < 1024; i += 512) lh[i] = 0;
            __syncthreads();
            for (int i = tid; i < cnt_e; i += 512)
                atomicAdd(&lh[dst[base_e + i] >> 6], 1);
            __syncthreads();
            const int lane = tid & 63;
            const int wid = tid >> 6;  // 8 waves
            int s0 = lh[tid * 2], s1 = lh[tid * 2 + 1];
            int tot = s0 + s1;
            int inc = tot;
#pragma unroll
            for (int off = 1; off < 64; off <<= 1) {
                int t = __shfl_up(inc, off, 64);
                if (lane >= off) inc += t;
            }
            if (lane == 63) wsum[wid] = inc;
            __syncthreads();
            int wbase = 0;
#pragma unroll
            for (int k = 0; k < 8; ++k)
                if (k < wid) wbase += wsum[k];
            int ebase = wbase + inc - tot;
            lex[tid * 2] = ebase;
            lex[tid * 2 + 1] = ebase + s0;
            for (int bb = tid; bb < NB; bb += 512) {
                int c = lh[bb];
                gbase_sh[bb] = c ? atomicAdd(&bucket_cursor[bb], c) : 0;
            }
            __syncthreads();
            for (int i = tid; i < 1024; i += 512) lh[i] = 0;  // reuse as cursor
            __syncthreads();
            for (int i = tid; i < cnt_e; i += 512) {
                int e = base_e + i;
                int d = dst[e];
                unsigned bb = (unsigned)d >> 6;
                int r = atomicAdd(&lh[bb], 1);
                sortedv[lex[bb] + r] =
                    (bb << 22) | ((unsigned)(d & 63) << 16) | (unsigned)(src[e] & 0xFFFF);
            }
            __syncthreads();
            for (int i = tid; i < cnt_e; i += 512) {
                unsigned v = sortedv[i];
                int bb = v >> 22;
                int pos = gbase_sh[bb] + (i - lex[bb]);
                if (pos < BSTRIDE)  // overflow guard (never hit for this input)
                    tmp[(size_t)bb * BSTRIDE + pos] = v;
            }
        } else {
            // ---- gemm1 body (512 threads: 4 rows x 4 cols per thread) ----
            float* xs = (float*)smem;  // 64*128 floats = 32 KB
            const int row0 = (item - nchunks) * 64;
            {
                const float4* s4 = (const float4*)h;
                float4* d4 = (float4*)xs;
                int base4 = row0 * 32;
                int tot4 = N * 32;
                for (int i = tid; i < 2048; i += 512)
                    if (base4 + i < tot4) d4[i] = s4[base4 + i];
            }
            __syncthreads();
            const int lane32 = tid & 31;
            const int c0 = lane32 * 4;
            const int r0 = (tid >> 5) * 4;  // 16 groups x 4 rows
            float acc[4][4] = {};
#pragma unroll 2
            for (int k0 = 0; k0 < 128; k0 += 4) {
                float4 wv0 = *(const float4*)(W1 + (k0 + 0) * 128 + c0);
                float4 wv1 = *(const float4*)(W1 + (k0 + 1) * 128 + c0);
                float4 wv2 = *(const float4*)(W1 + (k0 + 2) * 128 + c0);
                float4 wv3 = *(const float4*)(W1 + (k0 + 3) * 128 + c0);
                float4 xv[4];
#pragma unroll
                for (int r = 0; r < 4; ++r)
                    xv[r] = *(const float4*)(xs + (r0 + r) * 128 + k0);
#pragma unroll
                for (int r = 0; r < 4; ++r) {
                    acc[r][0] = fmaf(xv[r].x, wv0.x, acc[r][0]);
                    acc[r][1] = fmaf(xv[r].x, wv0.y, acc[r][1]);
                    acc[r][2] = fmaf(xv[r].x, wv0.z, acc[r][2]);
                    acc[r][3] = fmaf(xv[r].x, wv0.w, acc[r][3]);
                    acc[r][0] = fmaf(xv[r].y, wv1.x, acc[r][0]);
                    acc[r][1] = fmaf(xv[r].y, wv1.y, acc[r][1]);
                    acc[r][2] = fmaf(xv[r].y, wv1.z, acc[r][2]);
                    acc[r][3] = fmaf(xv[r].y, wv1.w, acc[r][3]);
                    acc[r][0] = fmaf(xv[r].z, wv2.x, acc[r][0]);
                    acc[r][1] = fmaf(xv[r].z, wv2.y, acc[r][1]);
                    acc[r][2] = fmaf(xv[r].z, wv2.z, acc[r][2]);
                    acc[r][3] = fmaf(xv[r].z, wv2.w, acc[r][3]);
                    acc[r][0] = fmaf(xv[r].w, wv3.x, acc[r][0]);
                    acc[r][1] = fmaf(xv[r].w, wv3.y, acc[r][1]);
                    acc[r][2] = fmaf(xv[r].w, wv3.z, acc[r][2]);
                    acc[r][3] = fmaf(xv[r].w, wv3.w, acc[r][3]);
                }
            }
            float4 alv = *(const float4*)(al1 + c0);
            float4 arv = *(const float4*)(ar1 + c0);
#pragma unroll
            for (int r = 0; r < 4; ++r) {
                int row = row0 + r0 + r;
                if (row < N) {
                    ushort4 fb;
                    fb.x = f2bf(acc[r][0]);
                    fb.y = f2bf(acc[r][1]);
                    fb.z = f2bf(acc[r][2]);
                    fb.w = f2bf(acc[r][3]);
                    *(ushort4*)(feat1b + (size_t)row * 128 + c0) = fb;
                    float pl = acc[r][0] * alv.x + acc[r][1] * alv.y +
                               acc[r][2] * alv.z + acc[r][3] * alv.w;
                    float pr = acc[r][0] * arv.x + acc[r][1] * arv.y +
                               acc[r][2] * arv.z + acc[r][3] * arv.w;
#pragma unroll
                    for (int off = 4; off >= 1; off >>= 1) {
                        pl += __shfl_xor(pl, off, 32);
                        pr += __shfl_xor(pr, off, 32);
                    }
                    if ((lane32 & 7) == 0) {
                        el1[row * 4 + (lane32 >> 3)] = pl;
                        er1[row * 4 + (lane32 >> 3)] = pr;
                    }
                }
            }
        }
        __syncthreads();
    }
    grid.sync();

    // ---------------- phase 2: gather1 (half-buckets) ----------------
    const int total2 = NB * 2;
    for (;;) {
        if (tid == 0) item_sh = atomicAdd(&qcnt[1], 1);
        __syncthreads();
        const int item = item_sh;
        if (item >= total2) break;
        {
            float* a_all = (float*)smem;     // 4096 floats (sval overlays)
            int* ssrc = smem + 4096;         // 1536
            int* dh = smem + 5632;
            int* dex = smem + 5696;
            int* dcur = smem + 5760;
            unsigned* sval = (unsigned*)a_all;
            const int b = item >> 1;
            const int half = item & 1;
            const int gb = b * BSTRIDE;
            const int cnt = min(bucket_cursor[b], BSTRIDE);
            if (tid < 64) dh[tid] = 0;
            __syncthreads();
            for (int i = tid; i < cnt; i += 512) {
                unsigned v = tmp[gb + i];
                sval[i] = v;
                atomicAdd(&dh[(v >> 16) & 63], 1);
            }
            __syncthreads();
            if (tid < 64) {
                int v = dh[tid], inc = v;
#pragma unroll
                for (int off = 1; off < 64; off <<= 1) {
                    int t = __shfl_up(inc, off, 64);
                    if (tid >= off) inc += t;
                }
                dex[tid] = inc - v;
                dcur[tid] = inc - v;
            }
            __syncthreads();
            for (int i = tid; i < cnt; i += 512) {
                unsigned val = sval[i];
                int dl = (val >> 16) & 63;
                int pos = atomicAdd(&dcur[dl], 1);
                ssrc[pos] = (int)((unsigned)(dl << 16) | (val & 0xFFFFu));
            }
            __syncthreads();
            const int begH = half ? dex[32] : 0;
            const int endH = half ? cnt : dex[32];
            for (int i = begH + tid; i < endH; i += 512) {
                int val = ssrc[i];
                int s = val & 0xFFFF;
                int dl = val >> 16;
                float4 el4 = *(const float4*)(el1 + (size_t)s * 4);
                float4 er4 = *(const float4*)(er1 + (size_t)(b * 64 + dl) * 4);
                float v0 = __expf(lrelu(el4.x + er4.x));
                float v1 = __expf(lrelu(el4.y + er4.y));
                float v2 = __expf(lrelu(el4.z + er4.z));
                float v3 = __expf(lrelu(el4.w + er4.w));
                int idx = i - begH;
                if (idx < 1024) *(float4*)&a_all[idx * 4] = make_float4(v0, v1, v2, v3);
            }
            __syncthreads();
            const int w = tid >> 6;
            const int lane = tid & 63;
            const int q = lane >> 4;
            const int l16 = lane & 15;
            const int c0 = l16 * 8;
            const int hh = l16 >> 2;
            float4 bv0 = *(const float4*)(b1 + c0);
            float4 bv1 = *(const float4*)(b1 + c0 + 4);
            for (int k = 0; k < 4; ++k) {
                const int dl = half * 32 + w * 4 + k;
                const int d = b * 64 + dl;
                if (d >= N) break;
                const int baseA = dex[dl];
                const int baseR = baseA - begH;
                const int M = dh[dl];
                float acc[8] = {}, bcc[8] = {};
                float den = 0.f;
                int e = q;
                for (; e + 12 < M; e += 16) {
                    int s0 = ssrc[baseA + e] & 0xFFFF;
                    int s1 = ssrc[baseA + e + 4] & 0xFFFF;
                    int s2 = ssrc[baseA + e + 8] & 0xFFFF;
                    int s3 = ssrc[baseA + e + 12] & 0xFFFF;
                    float a0 = a_all[(baseR + e) * 4 + hh];
                    float a1 = a_all[(baseR + e + 4) * 4 + hh];
                    float a2 = a_all[(baseR + e + 8) * 4 + hh];
                    float a3 = a_all[(baseR + e + 12) * 4 + hh];
                    uint4 f0 = *(const uint4*)(feat1b + (size_t)s0 * 128 + c0);
                    uint4 f1 = *(const uint4*)(feat1b + (size_t)s1 * 128 + c0);
                    uint4 f2 = *(const uint4*)(feat1b + (size_t)s2 * 128 + c0);
                    uint4 f3 = *(const uint4*)(feat1b + (size_t)s3 * 128 + c0);
                    den += (a0 + a1) + (a2 + a3);
                    FMA8(acc, f0, a0);
                    FMA8(bcc, f1, a1);
                    FMA8(acc, f2, a2);
                    FMA8(bcc, f3, a3);
                }
                for (; e < M; e += 4) {
                    int s0 = ssrc[baseA + e] & 0xFFFF;
                    float a0 = a_all[(baseR + e) * 4 + hh];
                    uint4 f0 = *(const uint4*)(feat1b + (size_t)s0 * 128 + c0);
                    den += a0;
                    FMA8(acc, f0, a0);
                }
#pragma unroll
                for (int j = 0; j < 8; ++j) {
                    acc[j] += bcc[j];
                    acc[j] += __shfl_xor(acc[j], 16, 64);
                    acc[j] += __shfl_xor(acc[j], 32, 64);
                }
                den += __shfl_xor(den, 16, 64);
                den += __shfl_xor(den, 32, 64);
                if (q == 0) {
                    float inv = (M > 0) ? 1.f / den : 0.f;
                    uint4 o;
                    o.x = pack2bf(fmaxf(acc[0] * inv + bv0.x, 0.f),
                                  fmaxf(acc[1] * inv + bv0.y, 0.f));
                    o.y = pack2bf(fmaxf(acc[2] * inv + bv0.z, 0.f),
                                  fmaxf(acc[3] * inv + bv0.w, 0.f));
                    o.z = pack2bf(fmaxf(acc[4] * inv + bv1.x, 0.f),
                                  fmaxf(acc[5] * inv + bv1.y, 0.f));
                    o.w = pack2bf(fmaxf(acc[6] * inv + bv1.z, 0.f),
                                  fmaxf(acc[7] * inv + bv1.w, 0.f));
                    *(uint4*)(out1b + (size_t)d * 128 + c0) = o;
                }
            }
        }
        __syncthreads();
    }
    grid.sync();

    // ---------------- phase 3: gemm2 tiles ----------------
    for (;;) {
        if (tid == 0) item_sh = atomicAdd(&qcnt[2], 1);
        __syncthreads();
        const int item = item_sh;
        if (item >= g1tiles) break;
        {
            float* xs = (float*)smem;  // 32 KB
            const int row0 = item * 64;
            {
                const uint4* s8 = (const uint4*)out1b;
                int base8 = row0 * 16;
                int tot8 = N * 16;
                for (int i = tid; i < 1024; i += 512)
                    if (base8 + i < tot8) {
                        uint4 v = s8[base8 + i];
                        float* o = xs + i * 8;
                        o[0] = bf2f_lo(v.x);
                        o[1] = bf2f_hi(v.x);
                        o[2] = bf2f_lo(v.y);
                        o[3] = bf2f_hi(v.y);
                        o[4] = bf2f_lo(v.z);
                        o[5] = bf2f_hi(v.z);
                        o[6] = bf2f_lo(v.w);
                        o[7] = bf2f_hi(v.w);
                    }
            }
            __syncthreads();
            const int l16 = tid & 15;
            const int c0 = l16 * 4;
            const int r0 = (tid >> 4) * 2;  // 32 groups x 2 rows
            float acc[2][4] = {};
            for (int k0 = 0; k0 < 128; k0 += 8) {
                float4 wv[8];
#pragma unroll
                for (int kk = 0; kk < 8; ++kk)
                    wv[kk] = *(const float4*)(W2 + (k0 + kk) * 64 + c0);
#pragma unroll
                for (int kk = 0; kk < 8; ++kk) {
                    float x0 = xs[(r0 + 0) * 128 + k0 + kk];
                    float x1 = xs[(r0 + 1) * 128 + k0 + kk];
                    acc[0][0] = fmaf(x0, wv[kk].x, acc[0][0]);
                    acc[0][1] = fmaf(x0, wv[kk].y, acc[0][1]);
                    acc[0][2] = fmaf(x0, wv[kk].z, acc[0][2]);
                    acc[0][3] = fmaf(x0, wv[kk].w, acc[0][3]);
                    acc[1][0] = fmaf(x1, wv[kk].x, acc[1][0]);
                    acc[1][1] = fmaf(x1, wv[kk].y, acc[1][1]);
                    acc[1][2] = fmaf(x1, wv[kk].z, acc[1][2]);
                    acc[1][3] = fmaf(x1, wv[kk].w, acc[1][3]);
                }
            }
            float4 alv = *(const float4*)(al2 + c0);
            float4 arv = *(const float4*)(ar2 + c0);
#pragma unroll
            for (int r = 0; r < 2; ++r) {
                int row = row0 + r0 + r;
                float pl = acc[r][0] * alv.x + acc[r][1] * alv.y +
                           acc[r][2] * alv.z + acc[r][3] * alv.w;
                float pr = acc[r][0] * arv.x + acc[r][1] * arv.y +
                           acc[r][2] * arv.z + acc[r][3] * arv.w;
#pragma unroll
                for (int off = 8; off >= 1; off >>= 1) {
                    pl += __shfl_xor(pl, off, 16);
                    pr += __shfl_xor(pr, off, 16);
                }
                if (row < N) {
                    ushort4 fb;
                    fb.x = f2bf(acc[r][0]);
                    fb.y = f2bf(acc[r][1]);
                    fb.z = f2bf(acc[r][2]);
                    fb.w = f2bf(acc[r][3]);
                    *(ushort4*)(feat2b + (size_t)row * 64 + c0) = fb;
                    if (l16 == 0) {
                        el2[row] = pl;
                        er2[row] = pr;
                    }
                }
            }
        }
        __syncthreads();
    }
    grid.sync();

    // ---------------- phase 4: gather2 (half-buckets) ----------------
    for (;;) {
        if (tid == 0) item_sh = atomicAdd(&qcnt[3], 1);
        __syncthreads();
        const int item = item_sh;
        if (item >= total2) break;
        {
            float* a_all = (float*)smem;   // 1536 floats (sval overlays)
            int* ssrc = smem + 1536;       // 1536
            int* dh = smem + 3072;
            int* dex = smem + 3136;
            int* dcur = smem + 3200;
            unsigned* sval = (unsigned*)a_all;
            const int b = item >> 1;
            const int half = item & 1;
            const int gb = b * BSTRIDE;
            const int cnt = min(bucket_cursor[b], BSTRIDE);
            if (tid < 64) dh[tid] = 0;
            __syncthreads();
            for (int i = tid; i < cnt; i += 512) {
                unsigned v = tmp[gb + i];
                sval[i] = v;
                atomicAdd(&dh[(v >> 16) & 63], 1);
            }
            __syncthreads();
            if (tid < 64) {
                int v = dh[tid], inc = v;
#pragma unroll
                for (int off = 1; off < 64; off <<= 1) {
                    int t = __shfl_up(inc, off, 64);
                    if (tid >= off) inc += t;
                }
                dex[tid] = inc - v;
                dcur[tid] = inc - v;
            }
            __syncthreads();
            for (int i = tid; i < cnt; i += 512) {
                unsigned val = sval[i];
                int dl = (val >> 16) & 63;
                int pos = atomicAdd(&dcur[dl], 1);
                ssrc[pos] = (int)((unsigned)(dl << 16) | (val & 0xFFFFu));
            }
            __syncthreads();
            const int begH = half ? dex[32] : 0;
            const int endH = half ? cnt : dex[32];
            for (int i = begH + tid; i < endH; i += 512) {
                int val = ssrc[i];
                int s = val & 0xFFFF;
                int dl = val >> 16;
                float v = el2[s] + er2[b * 64 + dl];
                a_all[i] = __expf(lrelu(v));
            }
            __syncthreads();
            const int w = tid >> 6;
            const int lane = tid & 63;
            const int oct = lane >> 3;
            const int l8 = lane & 7;
            const int c0 = l8 * 8;
            float4 bv0 = *(const float4*)(b2 + c0);
            float4 bv1 = *(const float4*)(b2 + c0 + 4);
            for (int k = 0; k < 4; ++k) {
                const int dl = half * 32 + w * 4 + k;
                const int d = b * 64 + dl;
                if (d >= N) break;
                const int base = dex[dl];
                const int M = dh[dl];
                float acc[8] = {}, bcc[8] = {};
                float den = 0.f;
                int e = oct;
                for (; e + 8 < M; e += 16) {
                    int s0 = ssrc[base + e] & 0xFFFF;
                    int s1 = ssrc[base + e + 8] & 0xFFFF;
                    float a0 = a_all[base + e];
                    float a1 = a_all[base + e + 8];
                    uint4 f0 = *(const uint4*)(feat2b + (size_t)s0 * 64 + c0);
                    uint4 f1 = *(const uint4*)(feat2b + (size_t)s1 * 64 + c0);
                    den += a0 + a1;
                    FMA8(acc, f0, a0);
                    FMA8(bcc, f1, a1);
                }
                while (e < M) {
                    int s0 = ssrc[base + e] & 0xFFFF;
                    float a0 = a_all[base + e];
                    uint4 f0 = *(const uint4*)(feat2b + (size_t)s0 * 64 + c0);
                    den += a0;
                    FMA8(acc, f0, a0);
                    e += 8;
                }
#pragma unroll
                for (int j = 0; j < 8; ++j) {
                    acc[j] += bcc[j];
                    acc[j] += __shfl_xor(acc[j], 8, 64);
                    acc[j] += __shfl_xor(acc[j], 16, 64);
                    acc[j] += __shfl_xor(acc[j], 32, 64);
                }
                den += __shfl_xor(den, 8, 64);
                den += __shfl_xor(den, 16, 64);
                den += __shfl_xor(den, 32, 64);
                if (oct == 0) {
                    float inv = (M > 0) ? 1.f / den : 0.f;
                    *(float4*)(out2 + (size_t)d * 64 + c0) =
                        make_float4(acc[0] * inv + bv0.x, acc[1] * inv + bv0.y,
                                    acc[2] * inv + bv0.z, acc[3] * inv + bv0.w);
                    *(float4*)(out2 + (size_t)d * 64 + c0 + 4) =
                        make_float4(acc[4] * inv + bv1.x, acc[5] * inv + bv1.y,
                                    acc[6] * inv + bv1.z, acc[7] * inv + bv1.w);
                }
            }
        }
        __syncthreads();
    }
}

// ===========================================================================
extern "C" void kernel_launch(void* const* d_in, const int* in_sizes, int n_in,
                              void* d_out, int out_size, void* d_ws, size_t ws_size,
                              hipStream_t stream) {
    const float* h   = (const float*)d_in[0];
    const int*   src = (const int*)d_in[1];
    const int*   dst = (const int*)d_in[2];
    const float* W1  = (const float*)d_in[3];
    const float* al1 = (const float*)d_in[4];
    const float* ar1 = (const float*)d_in[5];
    const float* b1  = (const float*)d_in[6];
    const float* W2  = (const float*)d_in[7];
    const float* al2 = (const float*)d_in[8];
    const float* ar2 = (const float*)d_in[9];
    const float* b2  = (const float*)d_in[10];

    const int N = in_sizes[0] / 128;  // 50000 (pack assumes N <= 65536)
    const int E = in_sizes[1];        // 800000
    const int NB = (N + 63) >> 6;     // 782 buckets

    char* ws = (char*)d_ws;
    size_t off = 0;
    auto alloc = [&](size_t elems) -> void* {  // elems are 4-byte units
        void* p = (void*)(ws + off);
        off += ((elems * 4 + 255) / 256) * 256;
        return p;
    };
    int* bucket_cursor = (int*)alloc(NB);
    int* qcnt          = (int*)alloc(8);
    unsigned* tmp      = (unsigned*)alloc((size_t)NB * BSTRIDE);
    float* el1   = (float*)alloc((size_t)N * 4);
    float* er1   = (float*)alloc((size_t)N * 4);
    unsigned short* feat1b = (unsigned short*)alloc((size_t)N * 64);  // N*128 bf16
    unsigned short* out1b  = (unsigned short*)alloc((size_t)N * 64);  // N*128 bf16
    float* el2   = (float*)alloc(N);
    float* er2   = (float*)alloc(N);
    unsigned short* feat2b = (unsigned short*)alloc((size_t)N * 32);  // N*64 bf16
    float* out2  = (float*)d_out;

    const int nchunks = (E + CH - 1) / CH;

    // grid sized to exact cooperative co-residency (cached across launches)
    static int gridBlocks = 0;
    if (gridBlocks == 0) {
        int maxb = 0;
        hipOccupancyMaxActiveBlocksPerMultiprocessor(&maxb, gat_all, 512, 0);
        if (maxb < 1) maxb = 1;
        hipDeviceProp_t prop;
        int dev = 0;
        hipGetDevice(&dev);
        hipGetDeviceProperties(&prop, dev);
        int cus = prop.multiProcessorCount > 0 ? prop.multiProcessorCount : 256;
        gridBlocks = maxb * cus;
        if (gridBlocks > 2048) gridBlocks = 2048;
    }

    int E_ = E, NB_ = NB, nchunks_ = nchunks, N_ = N;
    void* args[] = {
        (void*)&src, (void*)&dst, (void*)&h, (void*)&W1, (void*)&al1,
        (void*)&ar1, (void*)&b1, (void*)&W2, (void*)&al2, (void*)&ar2,
        (void*)&b2, (void*)&bucket_cursor, (void*)&qcnt, (void*)&tmp,
        (void*)&el1, (void*)&er1, (void*)&feat1b, (void*)&out1b,
        (void*)&el2, (void*)&er2, (void*)&feat2b, (void*)&out2,
        (void*)&E_, (void*)&NB_, (void*)&nchunks_, (void*)&N_};
    hipLaunchCooperativeKernel((const void*)gat_all, dim3(gridBlocks), dim3(512),
                               args, 0, stream);
}

// Round 9
// 198.700 us; speedup vs baseline: 6.1078x; 6.1078x over previous
//
#include <hip/hip_runtime.h>

#define NEG_SLOPE 0.2f
#define CH 4096      // edges per partition chunk
#define BSTRIDE 1536 // padded words per bucket (mean 1024, sigma 32 -> +16 sigma)

__device__ inline unsigned short f2bf(float f) {
    unsigned u = __float_as_uint(f);
    unsigned r = (u + 0x7FFFu + ((u >> 16) & 1u)) >> 16;
    return (unsigned short)r;
}
__device__ inline unsigned pack2bf(float a, float b) {
    return (unsigned)f2bf(a) | ((unsigned)f2bf(b) << 16);
}
__device__ inline float bf2f_lo(unsigned u) { return __uint_as_float(u << 16); }
__device__ inline float bf2f_hi(unsigned u) { return __uint_as_float(u & 0xFFFF0000u); }
__device__ inline float lrelu(float v) { return v > 0.f ? v : NEG_SLOPE * v; }

#define FMA8(A, F, S)                          \
    A[0] = fmaf(bf2f_lo((F).x), S, A[0]);      \
    A[1] = fmaf(bf2f_hi((F).x), S, A[1]);      \
    A[2] = fmaf(bf2f_lo((F).y), S, A[2]);      \
    A[3] = fmaf(bf2f_hi((F).y), S, A[3]);      \
    A[4] = fmaf(bf2f_lo((F).z), S, A[4]);      \
    A[5] = fmaf(bf2f_hi((F).z), S, A[5]);      \
    A[6] = fmaf(bf2f_lo((F).w), S, A[6]);      \
    A[7] = fmaf(bf2f_hi((F).w), S, A[7]);

// ===========================================================================
// FUSED: edge partition into fixed-stride padded buckets || gemm1.
// Packed edge: (b<<22)|((dst&63)<<16)|src  (requires N<=65536).
// ===========================================================================
__global__ __launch_bounds__(256) void csrP_gemm1_kernel(
    const int* __restrict__ src, const int* __restrict__ dst,
    int* __restrict__ bucket_cursor, unsigned* __restrict__ tmp, int E, int NB,
    int nchunks, const float* __restrict__ h, const float* __restrict__ W1,
    const float* __restrict__ al1, const float* __restrict__ ar1,
    unsigned short* __restrict__ feat1b, float* __restrict__ el1,
    float* __restrict__ er1, int N) {
    __shared__ __align__(16) int smem[8192];  // 32 KB union
    const int tid = threadIdx.x;
    if ((int)blockIdx.x < nchunks) {
        // ---------------- partition body (one pass, no global sync) --------
        int* lh = smem;                               // 1024 hist -> local cursor
        int* lex = smem + 1024;                       // 1024 local excl scan
        int* gbase_sh = smem + 2048;                  // 1024 global run bases
        int* wsum = smem + 3072;                      // 4 per-wave totals
        unsigned* sortedv = (unsigned*)(smem + 3104); // 4096
        const int base_e = blockIdx.x * CH;
        const int cnt_e = min(CH, E - base_e);
        for (int i = tid; i < 1024; i += 256) lh[i] = 0;
        __syncthreads();
        for (int i = tid; i < cnt_e; i += 256) atomicAdd(&lh[dst[base_e + i] >> 6], 1);
        __syncthreads();
        // local exclusive scan of lh (shfl-based)
        const int lane = tid & 63;
        const int wid = tid >> 6;
        int s0 = lh[tid * 4], s1 = lh[tid * 4 + 1], s2 = lh[tid * 4 + 2],
            s3 = lh[tid * 4 + 3];
        int tot = s0 + s1 + s2 + s3;
        int inc = tot;
#pragma unroll
        for (int off = 1; off < 64; off <<= 1) {
            int t = __shfl_up(inc, off, 64);
            if (lane >= off) inc += t;
        }
        if (lane == 63) wsum[wid] = inc;
        __syncthreads();
        int wbase = 0;
#pragma unroll
        for (int k = 0; k < 4; ++k)
            if (k < wid) wbase += wsum[k];
        int ebase = wbase + inc - tot;
        lex[tid * 4] = ebase;
        lex[tid * 4 + 1] = ebase + s0;
        lex[tid * 4 + 2] = ebase + s0 + s1;
        lex[tid * 4 + 3] = ebase + s0 + s1 + s2;
        // reserve contiguous run inside each bucket's padded slot
        for (int b = tid; b < NB; b += 256) {
            int c = lh[b];
            gbase_sh[b] = c ? atomicAdd(&bucket_cursor[b], c) : 0;
        }
        __syncthreads();
        for (int i = tid; i < 1024; i += 256) lh[i] = 0;  // reuse as local cursor
        __syncthreads();
        for (int i = tid; i < cnt_e; i += 256) {
            int e = base_e + i;
            int d = dst[e];
            unsigned b = (unsigned)d >> 6;
            int r = atomicAdd(&lh[b], 1);
            sortedv[lex[b] + r] =
                (b << 22) | ((unsigned)(d & 63) << 16) | (unsigned)(src[e] & 0xFFFF);
        }
        __syncthreads();
        for (int i = tid; i < cnt_e; i += 256) {
            unsigned v = sortedv[i];
            int b = v >> 22;
            int pos = gbase_sh[b] + (i - lex[b]);
            if (pos < BSTRIDE)  // overflow guard (never hit for this input)
                tmp[(size_t)b * BSTRIDE + pos] = v;
        }
    } else {
        // -------- gemm1 body: batched W1+LDS loads, unroll 2 ----------
        float* xs = (float*)smem;  // 64*128 floats = 32 KB
        const int row0 = ((int)blockIdx.x - nchunks) * 64;
        {
            const float4* s4 = (const float4*)h;
            float4* d4 = (float4*)xs;
            int base4 = row0 * 32;
            int tot4 = N * 32;
            for (int i = tid; i < 2048; i += 256)
                if (base4 + i < tot4) d4[i] = s4[base4 + i];
        }
        __syncthreads();
        const int lane = tid & 31;
        const int c0 = lane * 4;
        const int r0 = (tid >> 5) * 8;
        float acc[8][4] = {};
#pragma unroll 2
        for (int k0 = 0; k0 < 128; k0 += 4) {
            float4 wv0 = *(const float4*)(W1 + (k0 + 0) * 128 + c0);
            float4 wv1 = *(const float4*)(W1 + (k0 + 1) * 128 + c0);
            float4 wv2 = *(const float4*)(W1 + (k0 + 2) * 128 + c0);
            float4 wv3 = *(const float4*)(W1 + (k0 + 3) * 128 + c0);
            float4 xv[8];
#pragma unroll
            for (int r = 0; r < 8; ++r)
                xv[r] = *(const float4*)(xs + (r0 + r) * 128 + k0);
#pragma unroll
            for (int r = 0; r < 8; ++r) {
                acc[r][0] = fmaf(xv[r].x, wv0.x, acc[r][0]);
                acc[r][1] = fmaf(xv[r].x, wv0.y, acc[r][1]);
                acc[r][2] = fmaf(xv[r].x, wv0.z, acc[r][2]);
                acc[r][3] = fmaf(xv[r].x, wv0.w, acc[r][3]);
                acc[r][0] = fmaf(xv[r].y, wv1.x, acc[r][0]);
                acc[r][1] = fmaf(xv[r].y, wv1.y, acc[r][1]);
                acc[r][2] = fmaf(xv[r].y, wv1.z, acc[r][2]);
                acc[r][3] = fmaf(xv[r].y, wv1.w, acc[r][3]);
                acc[r][0] = fmaf(xv[r].z, wv2.x, acc[r][0]);
                acc[r][1] = fmaf(xv[r].z, wv2.y, acc[r][1]);
                acc[r][2] = fmaf(xv[r].z, wv2.z, acc[r][2]);
                acc[r][3] = fmaf(xv[r].z, wv2.w, acc[r][3]);
                acc[r][0] = fmaf(xv[r].w, wv3.x, acc[r][0]);
                acc[r][1] = fmaf(xv[r].w, wv3.y, acc[r][1]);
                acc[r][2] = fmaf(xv[r].w, wv3.z, acc[r][2]);
                acc[r][3] = fmaf(xv[r].w, wv3.w, acc[r][3]);
            }
        }
        float4 alv = *(const float4*)(al1 + c0);
        float4 arv = *(const float4*)(ar1 + c0);
#pragma unroll
        for (int r = 0; r < 8; ++r) {
            int row = row0 + r0 + r;
            if (row < N) {
                ushort4 fb;
                fb.x = f2bf(acc[r][0]);
                fb.y = f2bf(acc[r][1]);
                fb.z = f2bf(acc[r][2]);
                fb.w = f2bf(acc[r][3]);
                *(ushort4*)(feat1b + (size_t)row * 128 + c0) = fb;
                float pl = acc[r][0] * alv.x + acc[r][1] * alv.y + acc[r][2] * alv.z +
                           acc[r][3] * alv.w;
                float pr = acc[r][0] * arv.x + acc[r][1] * arv.y + acc[r][2] * arv.z +
                           acc[r][3] * arv.w;
#pragma unroll
                for (int off = 4; off >= 1; off >>= 1) {
                    pl += __shfl_xor(pl, off, 32);
                    pr += __shfl_xor(pr, off, 32);
                }
                if ((lane & 7) == 0) {
                    el1[row * 4 + (lane >> 3)] = pl;
                    er1[row * 4 + (lane >> 3)] = pr;
                }
            }
        }
    }
}

// ===========================================================================
// GEMM2: feat2b(bf16) = out1b(relu'd bf16) @ W2; el2/er2 fused. Batched
// W2 loads (8 in flight per k-group).
// ===========================================================================
__global__ __launch_bounds__(256) void gemm2_fused(const unsigned short* __restrict__ out1b,
                                                   const float* __restrict__ W2,
                                                   const float* __restrict__ al2,
                                                   const float* __restrict__ ar2,
                                                   unsigned short* __restrict__ feat2b,
                                                   float* __restrict__ el2,
                                                   float* __restrict__ er2, int N) {
    __shared__ float xs[64 * 128];  // 32 KB
    const int tid = threadIdx.x;
    const int row0 = blockIdx.x * 64;
    {
        const uint4* s8 = (const uint4*)out1b;  // 8 bf16 per uint4
        int base8 = row0 * 16;
        int tot8 = N * 16;
        for (int i = tid; i < 1024; i += 256)
            if (base8 + i < tot8) {
                uint4 v = s8[base8 + i];
                float* o = xs + i * 8;
                o[0] = bf2f_lo(v.x);
                o[1] = bf2f_hi(v.x);
                o[2] = bf2f_lo(v.y);
                o[3] = bf2f_hi(v.y);
                o[4] = bf2f_lo(v.z);
                o[5] = bf2f_hi(v.z);
                o[6] = bf2f_lo(v.w);
                o[7] = bf2f_hi(v.w);
            }
    }
    __syncthreads();
    const int lane = tid & 15;
    const int c0 = lane * 4;
    const int r0 = (tid >> 4) * 4;  // 16 groups x 4 rows = 64
    float acc[4][4] = {};
    for (int k0 = 0; k0 < 128; k0 += 8) {
        float4 wv[8];
#pragma unroll
        for (int kk = 0; kk < 8; ++kk)
            wv[kk] = *(const float4*)(W2 + (k0 + kk) * 64 + c0);
#pragma unroll
        for (int kk = 0; kk < 8; ++kk) {
#pragma unroll
            for (int r = 0; r < 4; ++r) {
                float x = xs[(r0 + r) * 128 + k0 + kk];
                acc[r][0] = fmaf(x, wv[kk].x, acc[r][0]);
                acc[r][1] = fmaf(x, wv[kk].y, acc[r][1]);
                acc[r][2] = fmaf(x, wv[kk].z, acc[r][2]);
                acc[r][3] = fmaf(x, wv[kk].w, acc[r][3]);
            }
        }
    }
    float4 alv = *(const float4*)(al2 + c0);
    float4 arv = *(const float4*)(ar2 + c0);
#pragma unroll
    for (int r = 0; r < 4; ++r) {
        int row = row0 + r0 + r;
        if (row < N) {
            ushort4 fb;
            fb.x = f2bf(acc[r][0]);
            fb.y = f2bf(acc[r][1]);
            fb.z = f2bf(acc[r][2]);
            fb.w = f2bf(acc[r][3]);
            *(ushort4*)(feat2b + (size_t)row * 64 + c0) = fb;
            float pl = acc[r][0] * alv.x + acc[r][1] * alv.y + acc[r][2] * alv.z +
                       acc[r][3] * alv.w;
            float pr = acc[r][0] * arv.x + acc[r][1] * arv.y + acc[r][2] * arv.z +
                       acc[r][3] * arv.w;
#pragma unroll
            for (int off = 8; off >= 1; off >>= 1) {
                pl += __shfl_xor(pl, off, 16);
                pr += __shfl_xor(pr, off, 16);
            }
            if (lane == 0) {
                el2[row] = pl;
                er2[row] = pr;
            }
        }
    }
}

// ===========================================================================
// Gather layer 1: 512 threads, 2 blocks/bucket. in-LDS sort + bulk scores,
// then ONE DST PER 16-LANE GROUP (8 waves x 4 groups = 32 dsts = half):
// no cross-lane reduction (each lane owns 8 cols + its head's full den),
// no per-dst serial walk, 16 edges in flight per wave (4 groups x 4-deep).
// ===========================================================================
__global__ __launch_bounds__(512) void gather1_kernel(const unsigned* __restrict__ tmp,
                                                      const int* __restrict__ bucket_cursor,
                                                      const float* __restrict__ el1,
                                                      const float* __restrict__ er1,
                                                      const unsigned short* __restrict__ feat1b,
                                                      const float* __restrict__ b1,
                                                      unsigned short* __restrict__ out1b,
                                                      int N) {
    __shared__ __align__(16) float a_all[4096];  // 16 KB; sval overlays first 6 KB
    __shared__ int ssrc[BSTRIDE];
    __shared__ int dh[64], dex[64], dcur[64];
    unsigned* sval = (unsigned*)a_all;
    const int tid = threadIdx.x;
    const int b = (int)blockIdx.x >> 1;
    const int half = (int)blockIdx.x & 1;
    const int gb = b * BSTRIDE;
    const int cnt = min(bucket_cursor[b], BSTRIDE);
    if (tid < 64) dh[tid] = 0;
    __syncthreads();
    for (int i = tid; i < cnt; i += 512) {
        unsigned v = tmp[gb + i];
        sval[i] = v;
        atomicAdd(&dh[(v >> 16) & 63], 1);
    }
    __syncthreads();
    if (tid < 64) {
        int v = dh[tid], inc = v;
#pragma unroll
        for (int off = 1; off < 64; off <<= 1) {
            int t = __shfl_up(inc, off, 64);
            if (tid >= off) inc += t;
        }
        dex[tid] = inc - v;
        dcur[tid] = inc - v;
    }
    __syncthreads();
    for (int i = tid; i < cnt; i += 512) {
        unsigned val = sval[i];
        int dl = (val >> 16) & 63;
        int pos = atomicAdd(&dcur[dl], 1);
        ssrc[pos] = (int)(val & 0xFFFFu);
    }
    __syncthreads();
    const int begH = half ? dex[32] : 0;
    const int endH = half ? cnt : dex[32];
    // ---- bulk score phase (overwrites sval region) ----
    {
        // recover dl for each sorted slot: slot i belongs to dl where
        // dex[dl] <= i < dex[dl]+dh[dl]; compute via per-dl loop is costly,
        // so instead re-pack: score pass iterates per dl chunk.
        // Simpler: iterate dls round-robin over waves.
        const int w = tid >> 6;
        const int lane = tid & 63;
        for (int dl = half * 32 + w * 4; dl < half * 32 + w * 4 + 4; ++dl) {
            const int base = dex[dl];
            const int M = dh[dl];
            float4 er4 = *(const float4*)(er1 + (size_t)(b * 64 + dl) * 4);
            for (int i = lane; i < M; i += 64) {
                int s = ssrc[base + i];
                float4 el4 = *(const float4*)(el1 + (size_t)s * 4);
                float v0 = __expf(lrelu(el4.x + er4.x));
                float v1 = __expf(lrelu(el4.y + er4.y));
                float v2 = __expf(lrelu(el4.z + er4.z));
                float v3 = __expf(lrelu(el4.w + er4.w));
                int idx = base + i - begH;
                if (idx < 1024)
                    *(float4*)&a_all[idx * 4] = make_float4(v0, v1, v2, v3);
            }
        }
    }
    __syncthreads();
    // ---- gather: one dst per 16-lane group ----
    const int w = tid >> 6;
    const int lane = tid & 63;
    const int g = lane >> 4;      // group 0..3 -> one dst each
    const int l16 = lane & 15;
    const int c0 = l16 * 8;       // 8 cols per lane
    const int hh = l16 >> 2;      // head of this lane's columns
    const int dl = half * 32 + w * 4 + g;
    const int d = b * 64 + dl;
    if (d < N) {
        const int baseA = dex[dl];
        const int baseR = baseA - begH;
        const int M = dh[dl];
        float4 bv0 = *(const float4*)(b1 + c0);
        float4 bv1 = *(const float4*)(b1 + c0 + 4);
        float acc[8] = {}, bcc[8] = {};
        float den = 0.f, dbn = 0.f;
        int e = 0;
        for (; e + 3 < M; e += 4) {
            int s0 = ssrc[baseA + e];
            int s1 = ssrc[baseA + e + 1];
            int s2 = ssrc[baseA + e + 2];
            int s3 = ssrc[baseA + e + 3];
            float a0 = a_all[(baseR + e) * 4 + hh];
            float a1 = a_all[(baseR + e + 1) * 4 + hh];
            float a2 = a_all[(baseR + e + 2) * 4 + hh];
            float a3 = a_all[(baseR + e + 3) * 4 + hh];
            uint4 f0 = *(const uint4*)(feat1b + (size_t)s0 * 128 + c0);
            uint4 f1 = *(const uint4*)(feat1b + (size_t)s1 * 128 + c0);
            uint4 f2 = *(const uint4*)(feat1b + (size_t)s2 * 128 + c0);
            uint4 f3 = *(const uint4*)(feat1b + (size_t)s3 * 128 + c0);
            den += a0 + a2;
            dbn += a1 + a3;
            FMA8(acc, f0, a0);
            FMA8(bcc, f1, a1);
            FMA8(acc, f2, a2);
            FMA8(bcc, f3, a3);
        }
        for (; e < M; ++e) {
            int s0 = ssrc[baseA + e];
            float a0 = a_all[(baseR + e) * 4 + hh];
            uint4 f0 = *(const uint4*)(feat1b + (size_t)s0 * 128 + c0);
            den += a0;
            FMA8(acc, f0, a0);
        }
        den += dbn;
        float inv = (M > 0) ? 1.f / den : 0.f;
        uint4 o;
        o.x = pack2bf(fmaxf((acc[0] + bcc[0]) * inv + bv0.x, 0.f),
                      fmaxf((acc[1] + bcc[1]) * inv + bv0.y, 0.f));
        o.y = pack2bf(fmaxf((acc[2] + bcc[2]) * inv + bv0.z, 0.f),
                      fmaxf((acc[3] + bcc[3]) * inv + bv0.w, 0.f));
        o.z = pack2bf(fmaxf((acc[4] + bcc[4]) * inv + bv1.x, 0.f),
                      fmaxf((acc[5] + bcc[5]) * inv + bv1.y, 0.f));
        o.w = pack2bf(fmaxf((acc[6] + bcc[6]) * inv + bv1.z, 0.f),
                      fmaxf((acc[7] + bcc[7]) * inv + bv1.w, 0.f));
        *(uint4*)(out1b + (size_t)d * 128 + c0) = o;
    }
}

// ===========================================================================
// Gather layer 2: 512 threads, ONE block per bucket (sort once). One dst per
// 8-lane group: 8 waves x 8 groups = 64 dsts. No reductions.
// ===========================================================================
__global__ __launch_bounds__(512) void gather2_kernel(const unsigned* __restrict__ tmp,
                                                      const int* __restrict__ bucket_cursor,
                                                      const float* __restrict__ el2,
                                                      const float* __restrict__ er2,
                                                      const unsigned short* __restrict__ feat2b,
                                                      const float* __restrict__ b2,
                                                      float* __restrict__ out2, int N) {
    __shared__ __align__(16) float a_all[BSTRIDE];  // union: sval during sort
    __shared__ int ssrc[BSTRIDE];
    __shared__ int dh[64], dex[64], dcur[64];
    unsigned* sval = (unsigned*)a_all;
    const int tid = threadIdx.x;
    const int b = (int)blockIdx.x;
    const int gb = b * BSTRIDE;
    const int cnt = min(bucket_cursor[b], BSTRIDE);
    if (tid < 64) dh[tid] = 0;
    __syncthreads();
    for (int i = tid; i < cnt; i += 512) {
        unsigned v = tmp[gb + i];
        sval[i] = v;
        atomicAdd(&dh[(v >> 16) & 63], 1);
    }
    __syncthreads();
    if (tid < 64) {
        int v = dh[tid], inc = v;
#pragma unroll
        for (int off = 1; off < 64; off <<= 1) {
            int t = __shfl_up(inc, off, 64);
            if (tid >= off) inc += t;
        }
        dex[tid] = inc - v;
        dcur[tid] = inc - v;
    }
    __syncthreads();
    for (int i = tid; i < cnt; i += 512) {
        unsigned val = sval[i];
        int dl = (val >> 16) & 63;
        int pos = atomicAdd(&dcur[dl], 1);
        ssrc[pos] = (int)((unsigned)(dl << 16) | (val & 0xFFFFu));
    }
    __syncthreads();
    // ---- bulk score phase (overwrites sval region; absolute index) ----
    for (int i = tid; i < cnt; i += 512) {
        int val = ssrc[i];
        int s = val & 0xFFFF;
        int dl = val >> 16;
        float v = el2[s] + er2[b * 64 + dl];
        a_all[i] = __expf(lrelu(v));
    }
    __syncthreads();
    // ---- gather: one dst per 8-lane group ----
    const int w = tid >> 6;
    const int lane = tid & 63;
    const int g = lane >> 3;     // group 0..7 -> one dst each
    const int l8 = lane & 7;
    const int c0 = l8 * 8;       // 8 cols per lane (8 lanes cover 64)
    const int dl = w * 8 + g;
    const int d = b * 64 + dl;
    if (d < N) {
        const int base = dex[dl];
        const int M = dh[dl];
        float4 bv0 = *(const float4*)(b2 + c0);
        float4 bv1 = *(const float4*)(b2 + c0 + 4);
        float acc[8] = {}, bcc[8] = {};
        float den = 0.f, dbn = 0.f;
        int e = 0;
        for (; e + 3 < M; e += 4) {
            int s0 = ssrc[base + e] & 0xFFFF;
            int s1 = ssrc[base + e + 1] & 0xFFFF;
            int s2 = ssrc[base + e + 2] & 0xFFFF;
            int s3 = ssrc[base + e + 3] & 0xFFFF;
            float a0 = a_all[base + e];
            float a1 = a_all[base + e + 1];
            float a2 = a_all[base + e + 2];
            float a3 = a_all[base + e + 3];
            uint4 f0 = *(const uint4*)(feat2b + (size_t)s0 * 64 + c0);
            uint4 f1 = *(const uint4*)(feat2b + (size_t)s1 * 64 + c0);
            uint4 f2 = *(const uint4*)(feat2b + (size_t)s2 * 64 + c0);
            uint4 f3 = *(const uint4*)(feat2b + (size_t)s3 * 64 + c0);
            den += a0 + a2;
            dbn += a1 + a3;
            FMA8(acc, f0, a0);
            FMA8(bcc, f1, a1);
            FMA8(acc, f2, a2);
            FMA8(bcc, f3, a3);
        }
        for (; e < M; ++e) {
            int s0 = ssrc[base + e] & 0xFFFF;
            float a0 = a_all[base + e];
            uint4 f0 = *(const uint4*)(feat2b + (size_t)s0 * 64 + c0);
            den += a0;
            FMA8(acc, f0, a0);
        }
        den += dbn;
        float inv = (M > 0) ? 1.f / den : 0.f;
        *(float4*)(out2 + (size_t)d * 64 + c0) =
            make_float4((acc[0] + bcc[0]) * inv + bv0.x, (acc[1] + bcc[1]) * inv + bv0.y,
                        (acc[2] + bcc[2]) * inv + bv0.z, (acc[3] + bcc[3]) * inv + bv0.w);
        *(float4*)(out2 + (size_t)d * 64 + c0 + 4) =
            make_float4((acc[4] + bcc[4]) * inv + bv1.x, (acc[5] + bcc[5]) * inv + bv1.y,
                        (acc[6] + bcc[6]) * inv + bv1.z, (acc[7] + bcc[7]) * inv + bv1.w);
    }
}

// ===========================================================================
extern "C" void kernel_launch(void* const* d_in, const int* in_sizes, int n_in,
                              void* d_out, int out_size, void* d_ws, size_t ws_size,
                              hipStream_t stream) {
    const float* h   = (const float*)d_in[0];
    const int*   src = (const int*)d_in[1];
    const int*   dst = (const int*)d_in[2];
    const float* W1  = (const float*)d_in[3];
    const float* al1 = (const float*)d_in[4];
    const float* ar1 = (const float*)d_in[5];
    const float* b1  = (const float*)d_in[6];
    const float* W2  = (const float*)d_in[7];
    const float* al2 = (const float*)d_in[8];
    const float* ar2 = (const float*)d_in[9];
    const float* b2  = (const float*)d_in[10];

    const int N = in_sizes[0] / 128;  // 50000 (pack assumes N <= 65536)
    const int E = in_sizes[1];        // 800000
    const int NB = (N + 63) >> 6;     // 782 buckets

    char* ws = (char*)d_ws;
    size_t off = 0;
    auto alloc = [&](size_t elems) -> void* {  // elems are 4-byte units
        void* p = (void*)(ws + off);
        off += ((elems * 4 + 255) / 256) * 256;
        return p;
    };
    int* bucket_cursor = (int*)alloc(NB);
    unsigned* tmp      = (unsigned*)alloc((size_t)NB * BSTRIDE);
    float* el1   = (float*)alloc((size_t)N * 4);
    float* er1   = (float*)alloc((size_t)N * 4);
    unsigned short* feat1b = (unsigned short*)alloc((size_t)N * 64);  // N*128 bf16
    unsigned short* out1b  = (unsigned short*)alloc((size_t)N * 64);  // N*128 bf16 (relu'd)
    float* el2   = (float*)alloc(N);
    float* er2   = (float*)alloc(N);
    unsigned short* feat2b = (unsigned short*)alloc((size_t)N * 32);  // N*64 bf16
    float* out2  = (float*)d_out;

    const int nchunks = (E + CH - 1) / CH;
    const int gemm1_blocks = (N + 63) / 64;

    // --- edge partition (padded buckets, no global sync) + layer-1 GEMM ---
    hipMemsetAsync(bucket_cursor, 0, (size_t)NB * 4, stream);
    csrP_gemm1_kernel<<<nchunks + gemm1_blocks, 256, 0, stream>>>(
        src, dst, bucket_cursor, tmp, E, NB, nchunks, h, W1, al1, ar1, feat1b,
        el1, er1, N);

    // --- layer 1 gather (one dst per 16-lane group, no reductions) ---
    gather1_kernel<<<NB * 2, 512, 0, stream>>>(tmp, bucket_cursor, el1, er1,
                                               feat1b, b1, out1b, N);

    // --- layer 2 ---
    gemm2_fused<<<(N + 63) / 64, 256, 0, stream>>>(out1b, W2, al2, ar2, feat2b, el2,
                                                   er2, N);
    gather2_kernel<<<NB, 512, 0, stream>>>(tmp, bucket_cursor, el2, er2,
                                           feat2b, b2, out2, N);
}